// Round 1
// baseline (122.358 us; speedup 1.0000x reference)
//
#include <hip/hip_runtime.h>
#include <math.h>

#define BC 4
#define NODES 4096
#define FEAT 64
#define OUT_DIM 32
#define NWORDS (NODES / 32)        // 128 mask words per row
#define NEG_FILL (-1e16f)

// ---------------------------------------------------------------------------
// Kernel A: z[b,n,d] = sum_f h[b,n,f] * W[f,d]
// One thread per output element; 32 consecutive threads share one h row
// (broadcast reads), writes coalesced.
// ---------------------------------------------------------------------------
__global__ void zk(const float* __restrict__ h, const float* __restrict__ W,
                   float* __restrict__ z) {
    int t = blockIdx.x * blockDim.x + threadIdx.x;   // < BC*NODES*OUT_DIM
    int d = t & (OUT_DIM - 1);
    int row = t >> 5;                                // b*NODES + n
    const float* hr = h + row * FEAT;
    float s = 0.f;
#pragma unroll
    for (int f = 0; f < FEAT; ++f)
        s = fmaf(hr[f], W[f * OUT_DIM + d], s);
    z[t] = s;
}

// ---------------------------------------------------------------------------
// Kernel B: dense adjacency bitmask from COO (atomicOr dedupes duplicates,
// matching the reference's .at[r,c].set(1.0) semantics).
// ---------------------------------------------------------------------------
__global__ void maskk(const int* __restrict__ arow, const int* __restrict__ acol,
                      unsigned int* __restrict__ mask, int n_edges) {
    int t = blockIdx.x * blockDim.x + threadIdx.x;
    if (t >= n_edges) return;
    int r = arow[t], c = acol[t];
    atomicOr(&mask[r * NWORDS + (c >> 5)], 1u << (c & 31));
}

// ---------------------------------------------------------------------------
// Kernel C: one wave (block=64) per (b, n) row.
//   phase 1: scan 128 mask words -> neighbor list in LDS (unique cols)
//   phase 2: lane-per-neighbor scores + online softmax across the wave,
//            lanes 0-31 own output dim d=lane for the aggregation.
// ---------------------------------------------------------------------------
__global__ __launch_bounds__(64) void gatk(const float* __restrict__ z,
                                           const unsigned int* __restrict__ mask,
                                           float* __restrict__ out) {
    __shared__ float zn[OUT_DIM];
    __shared__ unsigned short nbr[NODES];   // worst-case full row
    __shared__ int cnt;

    int blk = blockIdx.x;
    int b = blk >> 12;            // / NODES
    int n = blk & (NODES - 1);
    int lane = threadIdx.x;
    const float* zb = z + b * NODES * OUT_DIM;

    if (lane == 0) cnt = 0;
    if (lane < OUT_DIM) zn[lane] = zb[n * OUT_DIM + lane];
    __syncthreads();

    // ---- phase 1: gather neighbor indices (2 mask words per lane) ----
    const unsigned int* mrow = mask + n * NWORDS;
#pragma unroll
    for (int k = 0; k < 2; ++k) {
        int w = lane * 2 + k;
        unsigned int bits = mrow[w];
        while (bits) {
            int bit = __ffs(bits) - 1;
            bits &= bits - 1;
            int pos = atomicAdd(&cnt, 1);
            nbr[pos] = (unsigned short)(w * 32 + bit);
        }
    }
    __syncthreads();
    int count = cnt;

    // ---- phase 2: online softmax over neighbor chunks of 64 ----
    float m_run = -INFINITY;
    float l_run = 0.f;
    float acc = 0.f;              // lane<32: accumulator for dim d=lane

    for (int base = 0; base < count; base += 64) {
        int j = base + lane;
        bool valid = (j < count);
        int mi = valid ? (int)nbr[j] : 0;
        float s = -INFINITY;
        if (valid) {
            const float* zm = zb + mi * OUT_DIM;
            float t = 0.f;
#pragma unroll
            for (int d2 = 0; d2 < OUT_DIM; ++d2)
                t = fmaf(zn[d2], zm[d2], t);
            s = (t >= 0.f) ? t : 0.1f * t;      // LeakyReLU(0.1)
            if (s == 0.f) s = NEG_FILL;          // masked_fill(att==0, -1e16)
        }
        // wave max across 64 lanes
        float cmax = s;
        for (int off = 32; off > 0; off >>= 1)
            cmax = fmaxf(cmax, __shfl_xor(cmax, off));
        float m_new = fmaxf(m_run, cmax);
        float p = expf(s - m_new);               // -inf / -1e16 -> 0
        float psum = p;
        for (int off = 32; off > 0; off >>= 1)
            psum += __shfl_xor(psum, off);
        float alpha = (m_run == -INFINITY) ? 0.f : expf(m_run - m_new);
        l_run = l_run * alpha + psum;
        acc *= alpha;
        int lim = min(64, count - base);
        for (int j2 = 0; j2 < lim; ++j2) {
            float pj = __shfl(p, j2);
            int mj = __shfl(mi, j2);
            if (lane < OUT_DIM && pj != 0.f)
                acc = fmaf(pj, zb[mj * OUT_DIM + lane], acc);
        }
        m_run = m_new;
    }

    if (lane < OUT_DIM) {
        float o;
        if (m_run <= -1e15f) {
            // degenerate row: softmax uniform over ALL 4096 columns
            float ssum = 0.f;
            for (int m2 = 0; m2 < NODES; ++m2)
                ssum += zb[m2 * OUT_DIM + lane];
            o = ssum * (1.f / NODES);
        } else {
            o = acc / l_run;
        }
        out[(b * NODES + n) * OUT_DIM + lane] = o;
    }
}

// ---------------------------------------------------------------------------
extern "C" void kernel_launch(void* const* d_in, const int* in_sizes, int n_in,
                              void* d_out, int out_size, void* d_ws, size_t ws_size,
                              hipStream_t stream) {
    const float* h   = (const float*)d_in[0];
    const float* W   = (const float*)d_in[1];
    const int*   ar  = (const int*)d_in[2];
    const int*   ac  = (const int*)d_in[3];
    float* out = (float*)d_out;

    // ws layout: z (2 MB) | mask bitmap (2 MB)
    float* z = (float*)d_ws;
    unsigned int* mask =
        (unsigned int*)((char*)d_ws + (size_t)BC * NODES * OUT_DIM * sizeof(float));
    int n_edges = in_sizes[2];

    hipMemsetAsync(mask, 0, (size_t)NODES * NWORDS * sizeof(unsigned int), stream);
    zk<<<(BC * NODES * OUT_DIM) / 256, 256, 0, stream>>>(h, W, z);
    maskk<<<(n_edges + 255) / 256, 256, 0, stream>>>(ar, ac, mask, n_edges);
    gatk<<<BC * NODES, 64, 0, stream>>>(z, mask, out);
}

// Round 2
// 100.608 us; speedup vs baseline: 1.2162x; 1.2162x over previous
//
#include <hip/hip_runtime.h>
#include <math.h>

#define BC 4
#define NODES 4096
#define FEAT 64
#define OUT_DIM 32
#define NWORDS (NODES / 32)        // 128 mask words per row
#define NEG_FILL (-1e16f)
#define RPB 4                      // rows per block in gatk (1 wave per row)
#define MAXNBR 512                 // per-row neighbor cap (Poisson(32); P(>512)~0)

// ---------------------------------------------------------------------------
// Fused prep kernel, grid-partitioned:
//   blocks [0, zblocks):  z[b,n,:] = h[b,n,:] @ W   (float4-vectorized, 8 thr/row)
//   blocks [zblocks, ..): adjacency bitmask from COO (atomicOr dedupes, matching
//                         the reference's .at[r,c].set(1.0) semantics)
// ---------------------------------------------------------------------------
__global__ void prep(const float* __restrict__ h, const float* __restrict__ W,
                     const int* __restrict__ arow, const int* __restrict__ acol,
                     float* __restrict__ z, unsigned int* __restrict__ mask,
                     int n_edges, int zblocks) {
    if ((int)blockIdx.x < zblocks) {
        int t = blockIdx.x * 256 + threadIdx.x;   // < BC*NODES*8
        int g = t & 7;                            // which float4 of the out row
        int row = t >> 3;                         // b*NODES + n
        const float* hr = h + row * FEAT;
        const float4* W4 = (const float4*)W;      // W row f = 8 float4s
        float4 s = make_float4(0.f, 0.f, 0.f, 0.f);
#pragma unroll
        for (int f = 0; f < FEAT; ++f) {
            float hv = hr[f];
            float4 w = W4[f * 8 + g];
            s.x = fmaf(hv, w.x, s.x);
            s.y = fmaf(hv, w.y, s.y);
            s.z = fmaf(hv, w.z, s.z);
            s.w = fmaf(hv, w.w, s.w);
        }
        ((float4*)z)[t] = s;
    } else {
        int t = ((int)blockIdx.x - zblocks) * 256 + threadIdx.x;
        if (t < n_edges) {
            int r = arow[t], c = acol[t];
            atomicOr(&mask[r * NWORDS + (c >> 5)], 1u << (c & 31));
        }
    }
}

// ---------------------------------------------------------------------------
// gatk: 256-thread block = 4 waves, one row per wave (disjoint LDS slices).
//   phase 1: scan 128 mask words -> neighbor list via popcount + wave scan
//   phase 2: lane-per-neighbor scores (float4 dot) + online softmax,
//            aggregation 2 neighbors/iter using both 32-lane halves.
// ---------------------------------------------------------------------------
__global__ __launch_bounds__(256, 6) void gatk(const float* __restrict__ z,
                                               const unsigned int* __restrict__ mask,
                                               float* __restrict__ out) {
    __shared__ unsigned short nbr[RPB][MAXNBR];
    __shared__ float zns[RPB][OUT_DIM];

    int wave = threadIdx.x >> 6;
    int lane = threadIdx.x & 63;
    int blk = blockIdx.x * RPB + wave;     // global row id over BC*NODES
    int b = blk >> 12;
    int n = blk & (NODES - 1);
    const float* zb = z + b * NODES * OUT_DIM;

    if (lane < OUT_DIM) zns[wave][lane] = zb[n * OUT_DIM + lane];

    // ---- phase 1: neighbor compaction without atomics ----
    const unsigned int* mrow = mask + n * NWORDS;
    unsigned int w0 = mrow[lane * 2];
    unsigned int w1 = mrow[lane * 2 + 1];
    int myc = __popc(w0) + __popc(w1);
    int pre = myc;
#pragma unroll
    for (int off = 1; off < 64; off <<= 1) {
        int t = __shfl_up(pre, off);
        if (lane >= off) pre += t;
    }
    int total = __shfl(pre, 63);
    int posi = pre - myc;                  // exclusive prefix = my write offset
    unsigned short* mn = nbr[wave];
    int cbase = lane * 64;
    while (w0) { int bit = __ffs(w0) - 1; w0 &= w0 - 1; mn[posi++] = (unsigned short)(cbase + bit); }
    cbase += 32;
    while (w1) { int bit = __ffs(w1) - 1; w1 &= w1 - 1; mn[posi++] = (unsigned short)(cbase + bit); }
    __syncthreads();

    // ---- phase 2: online softmax over neighbor chunks of 64 ----
    float m_run = -INFINITY;
    float l_run = 0.f;
    float acc = 0.f;                       // per-half-wave accumulator for dim lane&31
    const float4* zn4 = (const float4*)zns[wave];
    const float4* zb4 = (const float4*)zb;
    int half = lane >> 5;
    int d = lane & 31;

    for (int base = 0; base < total; base += 64) {
        int j = base + lane;
        bool valid = (j < total);
        int mi = valid ? (int)mn[j] : 0;
        float s = -INFINITY;
        if (valid) {
            const float4* zm4 = zb4 + mi * 8;
            float t = 0.f;
#pragma unroll
            for (int q = 0; q < 8; ++q) {
                float4 a = zn4[q];
                float4 v = zm4[q];
                t = fmaf(a.x, v.x, t);
                t = fmaf(a.y, v.y, t);
                t = fmaf(a.z, v.z, t);
                t = fmaf(a.w, v.w, t);
            }
            s = (t >= 0.f) ? t : 0.1f * t;   // LeakyReLU(0.1)
            if (s == 0.f) s = NEG_FILL;      // masked_fill(att==0, -1e16)
        }
        float cmax = s;
#pragma unroll
        for (int off = 32; off > 0; off >>= 1)
            cmax = fmaxf(cmax, __shfl_xor(cmax, off));
        float m_new = fmaxf(m_run, cmax);
        float p = __expf(s - m_new);         // -inf / -1e16 -> 0
        float psum = p;
#pragma unroll
        for (int off = 32; off > 0; off >>= 1)
            psum += __shfl_xor(psum, off);
        float alpha = (m_run == -INFINITY) ? 0.f : __expf(m_run - m_new);
        l_run = l_run * alpha + psum;
        acc *= alpha;
        int lim = min(64, total - base);
        for (int j2 = 0; j2 < lim; j2 += 2) {
            int src = j2 + half;
            float pj = __shfl(p, src);
            int mj = __shfl(mi, src);
            if (src < lim && pj != 0.f)
                acc = fmaf(pj, zb[mj * OUT_DIM + d], acc);
        }
        m_run = m_new;
    }

    float up = __shfl_down(acc, 32);       // fold upper half into lower
    if (lane < OUT_DIM) {
        float o;
        if (m_run <= -1e15f) {
            // degenerate row: reference softmax uniform over ALL 4096 columns
            float ssum = 0.f;
            for (int m2 = 0; m2 < NODES; ++m2)
                ssum += zb[m2 * OUT_DIM + lane];
            o = ssum * (1.f / NODES);
        } else {
            o = (acc + up) / l_run;
        }
        out[blk * OUT_DIM + lane] = o;
    }
}

// ---------------------------------------------------------------------------
extern "C" void kernel_launch(void* const* d_in, const int* in_sizes, int n_in,
                              void* d_out, int out_size, void* d_ws, size_t ws_size,
                              hipStream_t stream) {
    const float* h  = (const float*)d_in[0];
    const float* W  = (const float*)d_in[1];
    const int*   ar = (const int*)d_in[2];
    const int*   ac = (const int*)d_in[3];
    float* out = (float*)d_out;

    // ws layout: z (2 MB) | mask bitmap (2 MB)
    float* z = (float*)d_ws;
    unsigned int* mask =
        (unsigned int*)((char*)d_ws + (size_t)BC * NODES * OUT_DIM * sizeof(float));
    int n_edges = in_sizes[2];

    int zblocks = (BC * NODES * 8) / 256;          // 512
    int eblocks = (n_edges + 255) / 256;           // 512

    hipMemsetAsync(mask, 0, (size_t)NODES * NWORDS * sizeof(unsigned int), stream);
    prep<<<zblocks + eblocks, 256, 0, stream>>>(h, W, ar, ac, z, mask, n_edges, zblocks);
    gatk<<<(BC * NODES) / RPB, 256, 0, stream>>>(z, mask, out);
}

// Round 3
// 90.367 us; speedup vs baseline: 1.3540x; 1.1133x over previous
//
#include <hip/hip_runtime.h>
#include <math.h>

#define BC 4
#define NODES 4096
#define FEAT 64
#define OUT_DIM 32
#define NWORDS (NODES / 32)        // 128 mask words per row
#define NEG_FILL (-1e16f)
#define RPB 4                      // rows per block in gatk (1 wave per row)
#define MAXNBR 512                 // per-row neighbor cap (Binomial(131072,1/4096); P(>512)~0)

// ---------------------------------------------------------------------------
// Fused prep kernel, grid-partitioned:
//   blocks [0, zblocks):  z[b,n,:] = h[b,n,:] @ W   (float4-vectorized, 8 thr/row)
//   blocks [zblocks, ..): adjacency bitmask from COO (atomicOr dedupes, matching
//                         the reference's .at[r,c].set(1.0) semantics)
// ---------------------------------------------------------------------------
__global__ void prep(const float* __restrict__ h, const float* __restrict__ W,
                     const int* __restrict__ arow, const int* __restrict__ acol,
                     float* __restrict__ z, unsigned int* __restrict__ mask,
                     int n_edges, int zblocks) {
    if ((int)blockIdx.x < zblocks) {
        int t = blockIdx.x * 256 + threadIdx.x;   // < BC*NODES*8
        int g = t & 7;                            // which float4 of the out row
        int row = t >> 3;                         // b*NODES + n
        const float4* hr4 = (const float4*)(h + row * FEAT);  // 16 float4s
        const float4* W4 = (const float4*)W;      // W row f = 8 float4s
        float4 s = make_float4(0.f, 0.f, 0.f, 0.f);
#pragma unroll
        for (int fq = 0; fq < 16; ++fq) {
            float4 hv = hr4[fq];
            float4 w0 = W4[(fq * 4 + 0) * 8 + g];
            float4 w1 = W4[(fq * 4 + 1) * 8 + g];
            float4 w2 = W4[(fq * 4 + 2) * 8 + g];
            float4 w3 = W4[(fq * 4 + 3) * 8 + g];
            s.x = fmaf(hv.x, w0.x, s.x); s.y = fmaf(hv.x, w0.y, s.y);
            s.z = fmaf(hv.x, w0.z, s.z); s.w = fmaf(hv.x, w0.w, s.w);
            s.x = fmaf(hv.y, w1.x, s.x); s.y = fmaf(hv.y, w1.y, s.y);
            s.z = fmaf(hv.y, w1.z, s.z); s.w = fmaf(hv.y, w1.w, s.w);
            s.x = fmaf(hv.z, w2.x, s.x); s.y = fmaf(hv.z, w2.y, s.y);
            s.z = fmaf(hv.z, w2.z, s.z); s.w = fmaf(hv.z, w2.w, s.w);
            s.x = fmaf(hv.w, w3.x, s.x); s.y = fmaf(hv.w, w3.y, s.y);
            s.z = fmaf(hv.w, w3.z, s.z); s.w = fmaf(hv.w, w3.w, s.w);
        }
        ((float4*)z)[t] = s;
    } else {
        int t = ((int)blockIdx.x - zblocks) * 256 + threadIdx.x;
        if (t < n_edges) {
            int r = arow[t], c = acol[t];
            atomicOr(&mask[r * NWORDS + (c >> 5)], 1u << (c & 31));
        }
    }
}

// ---------------------------------------------------------------------------
// gatk: 256-thread block = 4 waves, one row per wave. ALL LDS is wave-private
// (DS ops from one wave complete in order -> no __syncthreads anywhere).
//   phase 1: scan 128 mask words -> neighbor list via popcount + wave scan
//   phase 2: lane-per-neighbor scores (float4 dot) + online softmax;
//            aggregation via LDS-staged p, unrolled x4 per 32-lane half.
// ---------------------------------------------------------------------------
__global__ __launch_bounds__(256, 8) void gatk(const float* __restrict__ z,
                                               const unsigned int* __restrict__ mask,
                                               float* __restrict__ out) {
    __shared__ unsigned short nbr[RPB][MAXNBR];
    __shared__ float zns[RPB][OUT_DIM];
    __shared__ float ps[RPB][64];

    int wave = threadIdx.x >> 6;
    int lane = threadIdx.x & 63;
    int blk = blockIdx.x * RPB + wave;     // global row id over BC*NODES
    int b = blk >> 12;
    int n = blk & (NODES - 1);
    const float* zb = z + b * NODES * OUT_DIM;

    if (lane < OUT_DIM) zns[wave][lane] = zb[n * OUT_DIM + lane];

    // ---- phase 1: neighbor compaction (wave-local, no atomics) ----
    const uint2* mrow = (const uint2*)(mask + n * NWORDS);
    uint2 ww = mrow[lane];
    unsigned int w0 = ww.x, w1 = ww.y;
    int myc = __popc(w0) + __popc(w1);
    int pre = myc;
#pragma unroll
    for (int off = 1; off < 64; off <<= 1) {
        int t = __shfl_up(pre, off);
        if (lane >= off) pre += t;
    }
    int total = __shfl(pre, 63);
    int posi = pre - myc;                  // exclusive prefix = my write offset
    unsigned short* mn = nbr[wave];
    int cbase = lane * 64;
    while (w0) { int bit = __ffs(w0) - 1; w0 &= w0 - 1; mn[posi++] = (unsigned short)(cbase + bit); }
    cbase += 32;
    while (w1) { int bit = __ffs(w1) - 1; w1 &= w1 - 1; mn[posi++] = (unsigned short)(cbase + bit); }

    // ---- phase 2: online softmax over neighbor chunks of 64 ----
    float m_run = -INFINITY;
    float l_run = 0.f;
    float acc = 0.f;                       // per-half-wave accumulator for dim lane&31
    const float4* zn4 = (const float4*)zns[wave];
    const float4* zb4 = (const float4*)zb;
    float* psw = ps[wave];
    int half = lane >> 5;
    int d = lane & 31;

    for (int base = 0; base < total; base += 64) {
        int j = base + lane;
        bool valid = (j < total);
        int mi = valid ? (int)mn[j] : 0;
        float s = -INFINITY;
        if (valid) {
            const float4* zm4 = zb4 + mi * 8;
            float t = 0.f;
#pragma unroll
            for (int q = 0; q < 8; ++q) {
                float4 a = zn4[q];
                float4 v = zm4[q];
                t = fmaf(a.x, v.x, t);
                t = fmaf(a.y, v.y, t);
                t = fmaf(a.z, v.z, t);
                t = fmaf(a.w, v.w, t);
            }
            s = (t >= 0.f) ? t : 0.1f * t;   // LeakyReLU(0.1)
            if (s == 0.f) s = NEG_FILL;      // masked_fill(att==0, -1e16)
        }
        float cmax = s;
#pragma unroll
        for (int off = 32; off > 0; off >>= 1)
            cmax = fmaxf(cmax, __shfl_xor(cmax, off));
        float m_new = fmaxf(m_run, cmax);
        float p = __expf(s - m_new);         // -inf / -1e16 -> 0
        float psum = p;
#pragma unroll
        for (int off = 32; off > 0; off >>= 1)
            psum += __shfl_xor(psum, off);
        float alpha = (m_run == -INFINITY) ? 0.f : __expf(m_run - m_new);
        l_run = l_run * alpha + psum;
        acc *= alpha;
        m_run = m_new;

        // stage p for direct indexed access (wave-private LDS, in-order DS)
        psw[lane] = p;
        int lim = min(64, total - base);
        const unsigned short* mb = mn + base;
        int jj = half;
        while (jj + 6 < lim) {               // 4 neighbors per half per step
            float p0 = psw[jj],     p1 = psw[jj + 2],
                  p2 = psw[jj + 4], p3 = psw[jj + 6];
            int m0 = mb[jj],     m1 = mb[jj + 2],
                m2 = mb[jj + 4], m3 = mb[jj + 6];
            float v0 = zb[m0 * OUT_DIM + d];
            float v1 = zb[m1 * OUT_DIM + d];
            float v2 = zb[m2 * OUT_DIM + d];
            float v3 = zb[m3 * OUT_DIM + d];
            acc = fmaf(p0, v0, acc);
            acc = fmaf(p1, v1, acc);
            acc = fmaf(p2, v2, acc);
            acc = fmaf(p3, v3, acc);
            jj += 8;
        }
        while (jj < lim) {
            acc = fmaf(psw[jj], zb[mb[jj] * OUT_DIM + d], acc);
            jj += 2;
        }
    }

    float up = __shfl_down(acc, 32);       // fold upper half into lower
    if (lane < OUT_DIM) {
        float o;
        if (m_run <= -1e15f) {
            // degenerate row: reference softmax uniform over ALL 4096 columns
            float ssum = 0.f;
            for (int m2 = 0; m2 < NODES; ++m2)
                ssum += zb[m2 * OUT_DIM + lane];
            o = ssum * (1.f / NODES);
        } else {
            o = (acc + up) / l_run;
        }
        out[blk * OUT_DIM + lane] = o;
    }
}

// ---------------------------------------------------------------------------
extern "C" void kernel_launch(void* const* d_in, const int* in_sizes, int n_in,
                              void* d_out, int out_size, void* d_ws, size_t ws_size,
                              hipStream_t stream) {
    const float* h  = (const float*)d_in[0];
    const float* W  = (const float*)d_in[1];
    const int*   ar = (const int*)d_in[2];
    const int*   ac = (const int*)d_in[3];
    float* out = (float*)d_out;

    // ws layout: z (2 MB) | mask bitmap (2 MB)
    float* z = (float*)d_ws;
    unsigned int* mask =
        (unsigned int*)((char*)d_ws + (size_t)BC * NODES * OUT_DIM * sizeof(float));
    int n_edges = in_sizes[2];

    int zblocks = (BC * NODES * 8) / 256;          // 512
    int eblocks = (n_edges + 255) / 256;           // 512

    hipMemsetAsync(mask, 0, (size_t)NODES * NWORDS * sizeof(unsigned int), stream);
    prep<<<zblocks + eblocks, 256, 0, stream>>>(h, W, ar, ac, z, mask, n_edges, zblocks);
    gatk<<<(BC * NODES) / RPB, 256, 0, stream>>>(z, mask, out);
}

// Round 4
// 88.720 us; speedup vs baseline: 1.3792x; 1.0186x over previous
//
#include <hip/hip_runtime.h>
#include <math.h>

#define BC 4
#define NODES 4096
#define FEAT 64
#define OUT_DIM 32
#define NWORDS (NODES / 32)        // 128 mask words per row
#define NEG_FILL (-1e16f)
#define RPB 8                      // rows per block in gatk (2 rows per wave)
#define MAXNBR 512                 // per-row neighbor cap (Binomial(131072,1/4096); P(>512)~0)

// ---------------------------------------------------------------------------
// Fused prep kernel, grid-partitioned:
//   blocks [0, zblocks):  z[b,n,:] = h[b,n,:] @ W   (float4-vectorized, 8 thr/row)
//   blocks [zblocks, ..): adjacency bitmask from COO (atomicOr dedupes, matching
//                         the reference's .at[r,c].set(1.0) semantics)
// ---------------------------------------------------------------------------
__global__ void prep(const float* __restrict__ h, const float* __restrict__ W,
                     const int* __restrict__ arow, const int* __restrict__ acol,
                     float* __restrict__ z, unsigned int* __restrict__ mask,
                     int n_edges, int zblocks) {
    if ((int)blockIdx.x < zblocks) {
        int t = blockIdx.x * 256 + threadIdx.x;   // < BC*NODES*8
        int g = t & 7;                            // which float4 of the out row
        int row = t >> 3;                         // b*NODES + n
        const float4* hr4 = (const float4*)(h + row * FEAT);  // 16 float4s
        const float4* W4 = (const float4*)W;      // W row f = 8 float4s
        float4 s = make_float4(0.f, 0.f, 0.f, 0.f);
#pragma unroll
        for (int fq = 0; fq < 16; ++fq) {
            float4 hv = hr4[fq];
            float4 w0 = W4[(fq * 4 + 0) * 8 + g];
            float4 w1 = W4[(fq * 4 + 1) * 8 + g];
            float4 w2 = W4[(fq * 4 + 2) * 8 + g];
            float4 w3 = W4[(fq * 4 + 3) * 8 + g];
            s.x = fmaf(hv.x, w0.x, s.x); s.y = fmaf(hv.x, w0.y, s.y);
            s.z = fmaf(hv.x, w0.z, s.z); s.w = fmaf(hv.x, w0.w, s.w);
            s.x = fmaf(hv.y, w1.x, s.x); s.y = fmaf(hv.y, w1.y, s.y);
            s.z = fmaf(hv.y, w1.z, s.z); s.w = fmaf(hv.y, w1.w, s.w);
            s.x = fmaf(hv.z, w2.x, s.x); s.y = fmaf(hv.z, w2.y, s.y);
            s.z = fmaf(hv.z, w2.z, s.z); s.w = fmaf(hv.z, w2.w, s.w);
            s.x = fmaf(hv.w, w3.x, s.x); s.y = fmaf(hv.w, w3.y, s.y);
            s.z = fmaf(hv.w, w3.z, s.z); s.w = fmaf(hv.w, w3.w, s.w);
        }
        ((float4*)z)[t] = s;
    } else {
        int t = ((int)blockIdx.x - zblocks) * 256 + threadIdx.x;
        if (t < n_edges) {
            int r = arow[t], c = acol[t];
            atomicOr(&mask[r * NWORDS + (c >> 5)], 1u << (c & 31));
        }
    }
}

// ---------------------------------------------------------------------------
// gatk: 256-thread block = 4 waves, TWO rows per wave (one per 32-lane half).
// All LDS is half-wave-private -> no __syncthreads anywhere.
//   phase 1: 4 mask words/lane (uint4) -> neighbor list via popcount + scan(32)
//   phase 2: lane-per-neighbor scores (float4 dot) + online softmax (width-32
//            reductions); aggregation broadcasts p/m from LDS, lane=dim ->
//            one coalesced 128B z-row load per neighbor.
// Grid 2048 blocks x 8 blocks/CU -> every row co-resident (pure latency).
// ---------------------------------------------------------------------------
__global__ __launch_bounds__(256, 8) void gatk(const float* __restrict__ z,
                                               const unsigned int* __restrict__ mask,
                                               float* __restrict__ out) {
    __shared__ unsigned short nbr[RPB][MAXNBR];
    __shared__ float zns[RPB][OUT_DIM];
    __shared__ float ps[RPB][32];

    int wave = threadIdx.x >> 6;
    int lane = threadIdx.x & 63;
    int sub = lane >> 5;                   // which row of this wave
    int l = lane & 31;                     // lane within row == output dim
    int r = wave * 2 + sub;                // row slot within block
    int blk = blockIdx.x * RPB + r;        // global row id over BC*NODES
    int b = blk >> 12;
    int n = blk & (NODES - 1);
    const float* zb = z + b * NODES * OUT_DIM;

    zns[r][l] = zb[n * OUT_DIM + l];

    // ---- phase 1: neighbor compaction (half-wave-local) ----
    uint4 mw = ((const uint4*)(mask + n * NWORDS))[l];
    int myc = __popc(mw.x) + __popc(mw.y) + __popc(mw.z) + __popc(mw.w);
    int pre = myc;
#pragma unroll
    for (int off = 1; off < 32; off <<= 1) {
        int t = __shfl_up(pre, off, 32);
        if (l >= off) pre += t;
    }
    int total = __shfl(pre, 31, 32);
    int posi = pre - myc;                  // exclusive prefix = my write offset
    unsigned short* mn = nbr[r];
    {
        unsigned int w; int cb = l * 128;
        w = mw.x; while (w) { int bit = __ffs(w) - 1; w &= w - 1; mn[posi++] = (unsigned short)(cb + bit); }
        cb += 32;
        w = mw.y; while (w) { int bit = __ffs(w) - 1; w &= w - 1; mn[posi++] = (unsigned short)(cb + bit); }
        cb += 32;
        w = mw.z; while (w) { int bit = __ffs(w) - 1; w &= w - 1; mn[posi++] = (unsigned short)(cb + bit); }
        cb += 32;
        w = mw.w; while (w) { int bit = __ffs(w) - 1; w &= w - 1; mn[posi++] = (unsigned short)(cb + bit); }
    }

    // ---- phase 2: online softmax over neighbor chunks of 32 ----
    float m_run = -INFINITY;
    float l_run = 0.f;
    float acc = 0.f;                       // accumulator for dim l
    const float4* zn4 = (const float4*)zns[r];
    const float4* zb4 = (const float4*)zb;
    float* psw = ps[r];

    for (int base = 0; base < total; base += 32) {
        int j = base + l;
        bool valid = (j < total);
        int mi = valid ? (int)mn[j] : 0;
        float s = -INFINITY;
        if (valid) {
            const float4* zm4 = zb4 + mi * 8;
            float t = 0.f;
#pragma unroll
            for (int q = 0; q < 8; ++q) {
                float4 a = zn4[q];
                float4 v = zm4[q];
                t = fmaf(a.x, v.x, t);
                t = fmaf(a.y, v.y, t);
                t = fmaf(a.z, v.z, t);
                t = fmaf(a.w, v.w, t);
            }
            s = (t >= 0.f) ? t : 0.1f * t;   // LeakyReLU(0.1)
            if (s == 0.f) s = NEG_FILL;      // masked_fill(att==0, -1e16)
        }
        float cmax = s;
#pragma unroll
        for (int off = 16; off > 0; off >>= 1)
            cmax = fmaxf(cmax, __shfl_xor(cmax, off, 32));
        float m_new = fmaxf(m_run, cmax);
        float p = __expf(s - m_new);         // -inf / -1e16 -> 0
        float psum = p;
#pragma unroll
        for (int off = 16; off > 0; off >>= 1)
            psum += __shfl_xor(psum, off, 32);
        float alpha = (m_run == -INFINITY) ? 0.f : __expf(m_run - m_new);
        l_run = l_run * alpha + psum;
        acc *= alpha;
        m_run = m_new;

        // stage p; aggregation broadcasts p/m, lane=dim -> coalesced row loads
        psw[l] = p;
        int lim = min(32, total - base);
        const unsigned short* mb = mn + base;
        int jj = 0;
        while (jj + 3 < lim) {
            float p0 = psw[jj], p1 = psw[jj + 1], p2 = psw[jj + 2], p3 = psw[jj + 3];
            int m0 = mb[jj], m1 = mb[jj + 1], m2 = mb[jj + 2], m3 = mb[jj + 3];
            float v0 = zb[m0 * OUT_DIM + l];
            float v1 = zb[m1 * OUT_DIM + l];
            float v2 = zb[m2 * OUT_DIM + l];
            float v3 = zb[m3 * OUT_DIM + l];
            acc = fmaf(p0, v0, acc);
            acc = fmaf(p1, v1, acc);
            acc = fmaf(p2, v2, acc);
            acc = fmaf(p3, v3, acc);
            jj += 4;
        }
        while (jj < lim) {
            acc = fmaf(psw[jj], zb[mb[jj] * OUT_DIM + l], acc);
            ++jj;
        }
    }

    float o;
    if (m_run <= -1e15f) {
        // degenerate row: reference softmax uniform over ALL 4096 columns
        float ssum = 0.f;
        for (int m2 = 0; m2 < NODES; ++m2)
            ssum += zb[m2 * OUT_DIM + l];
        o = ssum * (1.f / NODES);
    } else {
        o = acc / l_run;
    }
    out[blk * OUT_DIM + l] = o;
}

// ---------------------------------------------------------------------------
extern "C" void kernel_launch(void* const* d_in, const int* in_sizes, int n_in,
                              void* d_out, int out_size, void* d_ws, size_t ws_size,
                              hipStream_t stream) {
    const float* h  = (const float*)d_in[0];
    const float* W  = (const float*)d_in[1];
    const int*   ar = (const int*)d_in[2];
    const int*   ac = (const int*)d_in[3];
    float* out = (float*)d_out;

    // ws layout: z (2 MB) | mask bitmap (2 MB)
    float* z = (float*)d_ws;
    unsigned int* mask =
        (unsigned int*)((char*)d_ws + (size_t)BC * NODES * OUT_DIM * sizeof(float));
    int n_edges = in_sizes[2];

    int zblocks = (BC * NODES * 8) / 256;          // 512
    int eblocks = (n_edges + 255) / 256;           // 512

    hipMemsetAsync(mask, 0, (size_t)NODES * NWORDS * sizeof(unsigned int), stream);
    prep<<<zblocks + eblocks, 256, 0, stream>>>(h, W, ar, ac, z, mask, n_edges, zblocks);
    gatk<<<(BC * NODES) / RPB, 256, 0, stream>>>(z, mask, out);
}